// Round 1
// baseline (2005.628 us; speedup 1.0000x reference)
//
// EncoderModel forward, MI355X/gfx950. Round 0: correctness-first MFMA pipeline.
// - GEMMs: bf16 MFMA 16x16x32, BM=BN=128 BK=32, 4 waves, global_load_lds(16B)
//   staging with XOR-swizzled source (linear LDS dest), split hi/lo bf16
//   activations for accuracy (weights single bf16).
// - Attention: 1 block per (b,h); K + V^T fully in swizzled LDS (144KB),
//   f32 softmax in registers, per-wave P redistribution via private LDS.
// - Residual / LN / softmax in f32. Output f32.
#include <hip/hip_runtime.h>

#define BB 32
#define SS 512
#define DD 512
#define HH 8
#define HDH 64
#define LL 6
#define DFF 2048
#define MM (BB*SS)

typedef __attribute__((ext_vector_type(4))) float f32x4;
typedef __attribute__((ext_vector_type(8))) short s16x8;
typedef __attribute__((ext_vector_type(4))) short s16x4;

__device__ __forceinline__ unsigned short f2bf(float f) {
    union { float f; unsigned u; } v; v.f = f;
    unsigned r = v.u + 0x7fffu + ((v.u >> 16) & 1u);
    return (unsigned short)(r >> 16);
}
__device__ __forceinline__ float bf2f(unsigned short b) {
    union { unsigned u; float f; } v; v.u = ((unsigned)b) << 16;
    return v.f;
}

__device__ __forceinline__ f32x4 mfma_bf16(s16x8 a, s16x8 b, f32x4 c) {
    asm("v_mfma_f32_16x16x32_bf16 %0, %1, %2, %0" : "+v"(c) : "v"(a), "v"(b));
    return c;
}

__device__ __forceinline__ void gload_lds16(const void* g, void* l) {
    __builtin_amdgcn_global_load_lds(
        (__attribute__((address_space(1))) void*)g,
        (__attribute__((address_space(3))) void*)l, 16, 0, 0);
}

// ---- weight conversion: Wq/Wk/Wv [L][H][D][HD] -> bf16 [L][N=H*HD][K=D] ----
__global__ __launch_bounds__(256) void k_conv_qkv(const float* __restrict__ src,
                                                  unsigned short* __restrict__ dst) {
    int i = blockIdx.x * 256 + threadIdx.x;          // over L*512*512
    if (i >= LL*DD*DD) return;
    int l = i >> 18;
    int n = (i >> 9) & 511;
    int kk = i & 511;
    int h = n >> 6, e = n & 63;
    dst[i] = f2bf(src[(((size_t)l*HH + h)*DD + kk)*HDH + e]);
}

// ---- generic: src [L][K][N] f32 -> dst [L][N][K] bf16 (K,N powers of 2) ----
__global__ __launch_bounds__(256) void k_conv_t(const float* __restrict__ src,
                                                unsigned short* __restrict__ dst,
                                                int logK, int logN) {
    int i = blockIdx.x * 256 + threadIdx.x;
    if (i >= (LL << (logK + logN))) return;
    int l = i >> (logK + logN);
    int n = (i >> logK) & ((1 << logN) - 1);
    int kk = i & ((1 << logK) - 1);
    dst[i] = f2bf(src[((size_t)l << (logK + logN)) + ((size_t)kk << logN) + n]);
}

// ---- embedding + positional encoding; writes f32 x and split bf16 copies ----
__global__ __launch_bounds__(256) void k_embed(const int* __restrict__ tokens,
                                               const float* __restrict__ emb,
                                               const float* __restrict__ pe,
                                               float* __restrict__ x,
                                               unsigned short* __restrict__ xh,
                                               unsigned short* __restrict__ xl) {
    int i = blockIdx.x * 256 + threadIdx.x;          // MM*128 float4's
    int row = i >> 7;
    int d4 = (i & 127) * 4;
    int srow = row & (SS - 1);
    int tok = tokens[row];
    f32x4 ev = *(const f32x4*)(emb + (size_t)tok*DD + d4);
    f32x4 pv = *(const f32x4*)(pe + (size_t)srow*DD + d4);
    f32x4 vv; s16x4 hv, lv;
    #pragma unroll
    for (int j = 0; j < 4; ++j) {
        vv[j] = ev[j] + pv[j];
        unsigned short hi = f2bf(vv[j]);
        hv[j] = (short)hi;
        lv[j] = (short)f2bf(vv[j] - bf2f(hi));
    }
    *(f32x4*)(x + (size_t)row*DD + d4) = vv;
    *(s16x4*)(xh + (size_t)row*DD + d4) = hv;
    *(s16x4*)(xl + (size_t)row*DD + d4) = lv;
}

// ---- fused residual + layernorm; writes f32 x_out and split bf16 copies ----
__global__ __launch_bounds__(128) void k_ln(const float* __restrict__ x,
                                            const float* __restrict__ y,
                                            const float* __restrict__ gg,
                                            const float* __restrict__ bb,
                                            float* __restrict__ xo,
                                            unsigned short* __restrict__ xh,
                                            unsigned short* __restrict__ xl) {
    const int row = blockIdx.x;
    const int tid = threadIdx.x;
    __shared__ float red[4];
    f32x4 xv = *(const f32x4*)(x + (size_t)row*DD + tid*4);
    f32x4 yv = *(const f32x4*)(y + (size_t)row*DD + tid*4);
    f32x4 vv;
    #pragma unroll
    for (int j = 0; j < 4; ++j) vv[j] = xv[j] + yv[j];
    float sum = vv[0] + vv[1] + vv[2] + vv[3];
    #pragma unroll
    for (int off = 1; off < 64; off <<= 1) sum += __shfl_xor(sum, off);
    if ((tid & 63) == 0) red[tid >> 6] = sum;
    __syncthreads();
    float mu = (red[0] + red[1]) * (1.0f / 512.0f);
    float s2 = 0.0f;
    #pragma unroll
    for (int j = 0; j < 4; ++j) { float d = vv[j] - mu; s2 += d * d; }
    #pragma unroll
    for (int off = 1; off < 64; off <<= 1) s2 += __shfl_xor(s2, off);
    if ((tid & 63) == 0) red[2 + (tid >> 6)] = s2;
    __syncthreads();
    float var = (red[2] + red[3]) * (1.0f / 512.0f);
    float rs = rsqrtf(var + 1e-5f);
    f32x4 gv = *(const f32x4*)(gg + tid*4);
    f32x4 bv = *(const f32x4*)(bb + tid*4);
    f32x4 ov; s16x4 hv, lv;
    #pragma unroll
    for (int j = 0; j < 4; ++j) {
        float o = (vv[j] - mu) * rs * gv[j] + bv[j];
        ov[j] = o;
        unsigned short hi = f2bf(o);
        hv[j] = (short)hi;
        lv[j] = (short)f2bf(o - bf2f(hi));
    }
    *(f32x4*)(xo + (size_t)row*DD + tid*4) = ov;
    *(s16x4*)(xh + (size_t)row*DD + tid*4) = hv;
    *(s16x4*)(xl + (size_t)row*DD + tid*4) = lv;
}

// ---- GEMM: C[M,N] = (Ah+Al)[M,K] @ Bt[N,K]^T, bf16 MFMA, split-A option ----
// EPI: 0 = bf16 out, 1 = f32 out, 2 = bf16 gelu(out+bias), 3 = f32 out+bias
template<int EPI, bool SPLIT>
__global__ __launch_bounds__(256, 2) void k_gemm(
    const unsigned short* __restrict__ Ah, const unsigned short* __restrict__ Al,
    const unsigned short* __restrict__ Bt,
    unsigned short* __restrict__ ob, float* __restrict__ of,
    const float* __restrict__ bias, int N, int K, int lgy)
{
    __shared__ short lds[2][3][4096];   // [buf][Ah,Al,B][128 rows x 32 bf16]
    const int tid = threadIdx.x;
    const int lane = tid & 63;
    const int wid = tid >> 6;
    const int g = lane >> 4;
    const int t16 = lane & 15;

    // XCD-aware bijective swizzle (grid always divisible by 8 here)
    int nwg = gridDim.x;
    int bid = blockIdx.x;
    int cpx = nwg >> 3;
    int swz = (bid & 7) * cpx + (bid >> 3);
    int bm = swz >> lgy;
    int bn = swz & ((1 << lgy) - 1);

    const unsigned short* Ag0 = Ah + (size_t)bm * 128 * K;
    const unsigned short* Ag1 = SPLIT ? (Al + (size_t)bm * 128 * K) : Ah;
    const unsigned short* Bg  = Bt + (size_t)bn * 128 * K;

    auto stage = [&](int buf, int k0) {
        #pragma unroll
        for (int i = 0; i < 2; ++i) {
            int slot = i * 256 + tid;
            int r = slot >> 2;
            int j = slot & 3;
            int js = j ^ ((r >> 1) & 3);       // source-side swizzle (involution)
            size_t go = (size_t)r * K + k0 + js * 8;
            int lo = i * 2048 + wid * 512;     // wave-uniform LDS base (shorts)
            gload_lds16(Ag0 + go, &lds[buf][0][lo]);
            if (SPLIT) gload_lds16(Ag1 + go, &lds[buf][1][lo]);
            gload_lds16(Bg + go, &lds[buf][2][lo]);
        }
    };

    f32x4 acc[4][4];
    #pragma unroll
    for (int a_ = 0; a_ < 4; ++a_)
        #pragma unroll
        for (int b_ = 0; b_ < 4; ++b_) acc[a_][b_] = (f32x4){0.f, 0.f, 0.f, 0.f};

    const int wm = wid >> 1, wn = wid & 1;
    stage(0, 0);
    __syncthreads();
    int nk = K >> 5;
    int buf = 0;
    for (int kt = 0; kt < nk; ++kt) {
        if (kt + 1 < nk) stage(buf ^ 1, (kt + 1) << 5);
        s16x8 af[4], alf[4], bf_[4];
        #pragma unroll
        for (int mt = 0; mt < 4; ++mt) {
            int r = wm * 64 + mt * 16 + t16;
            int off = r * 32 + ((g ^ ((r >> 1) & 3)) << 3);
            af[mt] = *(const s16x8*)&lds[buf][0][off];
            if (SPLIT) alf[mt] = *(const s16x8*)&lds[buf][1][off];
        }
        #pragma unroll
        for (int nt = 0; nt < 4; ++nt) {
            int r = wn * 64 + nt * 16 + t16;
            bf_[nt] = *(const s16x8*)&lds[buf][2][r * 32 + ((g ^ ((r >> 1) & 3)) << 3)];
        }
        #pragma unroll
        for (int mt = 0; mt < 4; ++mt)
            #pragma unroll
            for (int nt = 0; nt < 4; ++nt) {
                acc[mt][nt] = mfma_bf16(af[mt], bf_[nt], acc[mt][nt]);
                if (SPLIT) acc[mt][nt] = mfma_bf16(alf[mt], bf_[nt], acc[mt][nt]);
            }
        __syncthreads();
        buf ^= 1;
    }

    #pragma unroll
    for (int mt = 0; mt < 4; ++mt)
        #pragma unroll
        for (int nt = 0; nt < 4; ++nt) {
            int row0 = bm * 128 + wm * 64 + mt * 16 + g * 4;
            int col  = bn * 128 + wn * 64 + nt * 16 + t16;
            f32x4 v = acc[mt][nt];
            float bv = (EPI == 2 || EPI == 3) ? bias[col] : 0.0f;
            #pragma unroll
            for (int r_ = 0; r_ < 4; ++r_) {
                size_t idx = (size_t)(row0 + r_) * N + col;
                if (EPI == 0) {
                    ob[idx] = f2bf(v[r_]);
                } else if (EPI == 1) {
                    of[idx] = v[r_];
                } else if (EPI == 2) {
                    float tv = v[r_] + bv;
                    float ge = 0.5f * tv * (1.0f + erff(tv * 0.70710678118f));
                    ob[idx] = f2bf(ge);
                } else {
                    of[idx] = v[r_] + bv;
                }
            }
        }
}

// ---- attention: one block per (b,h); 8 waves; K,V^T in LDS; o split out ----
__global__ __launch_bounds__(512, 2) void k_attn(
    const unsigned short* __restrict__ q, const unsigned short* __restrict__ k,
    const unsigned short* __restrict__ v, const int* __restrict__ mask,
    unsigned short* __restrict__ oh, unsigned short* __restrict__ ol)
{
    extern __shared__ short smem[];
    short* Kl = smem;                        // [512][64] bf16, blk ^= (t&7)
    short* Vl = smem + 32768;                // [64][512] bf16, blk ^= (e&7)
    const int tid = threadIdx.x;
    const int lane = tid & 63, wid = tid >> 6;
    short* Pl = smem + 65536 + wid * 1024;   // per-wave [16][64] bf16
    const int bh = blockIdx.x;
    const int b = bh >> 3, h = bh & 7;
    const unsigned short* qb = q + (size_t)b * SS * DD + h * HDH;
    const unsigned short* kb = k + (size_t)b * SS * DD + h * HDH;
    const unsigned short* vb = v + (size_t)b * SS * DD + h * HDH;

    for (int c = tid; c < 4096; c += 512) {
        int t = c >> 3, j = c & 7;
        s16x8 kv = *(const s16x8*)(kb + (size_t)t * DD + j * 8);
        *(s16x8*)(Kl + t * 64 + ((j ^ (t & 7)) << 3)) = kv;
        s16x8 vv = *(const s16x8*)(vb + (size_t)t * DD + j * 8);
        #pragma unroll
        for (int m = 0; m < 8; ++m) {
            int e = j * 8 + m;
            Vl[e * 512 + (((t >> 3) ^ (e & 7)) << 3) + (t & 7)] = vv[m];
        }
    }
    const int g = lane >> 4, t16 = lane & 15;
    unsigned mbits = 0;
    for (int n2 = 0; n2 < 32; ++n2)
        if (mask[b * SS + n2 * 16 + t16] != 0) mbits |= (1u << n2);
    __syncthreads();

    for (int qi = 0; qi < 4; ++qi) {
        const int q0 = (wid * 4 + qi) * 16;
        s16x8 aq[2];
        #pragma unroll
        for (int ks = 0; ks < 2; ++ks)
            aq[ks] = *(const s16x8*)(qb + (size_t)(q0 + t16) * DD + ks * 32 + g * 8);

        f32x4 s[32];
        #pragma unroll
        for (int n2 = 0; n2 < 32; ++n2) s[n2] = (f32x4){0.f, 0.f, 0.f, 0.f};
        #pragma unroll
        for (int n2 = 0; n2 < 32; ++n2) {
            int t = n2 * 16 + t16;
            #pragma unroll
            for (int ks = 0; ks < 2; ++ks) {
                int blk = ks * 4 + g;
                s16x8 bk = *(const s16x8*)(Kl + t * 64 + ((blk ^ (t & 7)) << 3));
                s[n2] = mfma_bf16(aq[ks], bk, s[n2]);
            }
        }
        // softmax (f32, rows live in 16-lane groups)
        #pragma unroll
        for (int n2 = 0; n2 < 32; ++n2) {
            bool val = (mbits >> n2) & 1u;
            #pragma unroll
            for (int r_ = 0; r_ < 4; ++r_)
                s[n2][r_] = val ? s[n2][r_] * 0.125f : -3.0e38f;
        }
        float mx[4], inv[4];
        #pragma unroll
        for (int r_ = 0; r_ < 4; ++r_) {
            float m = -3.0e38f;
            #pragma unroll
            for (int n2 = 0; n2 < 32; ++n2) m = fmaxf(m, s[n2][r_]);
            #pragma unroll
            for (int off = 1; off < 16; off <<= 1) m = fmaxf(m, __shfl_xor(m, off));
            mx[r_] = m;
        }
        float sm[4] = {0.f, 0.f, 0.f, 0.f};
        #pragma unroll
        for (int n2 = 0; n2 < 32; ++n2)
            #pragma unroll
            for (int r_ = 0; r_ < 4; ++r_) {
                float p = __expf(s[n2][r_] - mx[r_]);
                s[n2][r_] = p;
                sm[r_] += p;
            }
        #pragma unroll
        for (int r_ = 0; r_ < 4; ++r_) {
            float t = sm[r_];
            #pragma unroll
            for (int off = 1; off < 16; off <<= 1) t += __shfl_xor(t, off);
            inv[r_] = 1.0f / t;
        }
        // PV through per-wave LDS redistribution, 64-key chunks
        f32x4 oacc[4];
        #pragma unroll
        for (int eo = 0; eo < 4; ++eo) oacc[eo] = (f32x4){0.f, 0.f, 0.f, 0.f};
        #pragma unroll
        for (int c4 = 0; c4 < 8; ++c4) {
            #pragma unroll
            for (int k4 = 0; k4 < 4; ++k4) {
                int n2 = c4 * 4 + k4;
                #pragma unroll
                for (int r_ = 0; r_ < 4; ++r_) {
                    int qq = g * 4 + r_;
                    int kk = k4 * 16 + t16;
                    Pl[qq * 64 + (((kk >> 3) ^ (qq & 7)) << 3) + (kk & 7)] =
                        (short)f2bf(s[n2][r_] * inv[r_]);
                }
            }
            #pragma unroll
            for (int ks2 = 0; ks2 < 2; ++ks2) {
                int kk = ks2 * 32 + g * 8;
                s16x8 pa = *(const s16x8*)(Pl + t16 * 64 + (((kk >> 3) ^ (t16 & 7)) << 3));
                int tg = c4 * 64 + kk;
                #pragma unroll
                for (int eo = 0; eo < 4; ++eo) {
                    int e = eo * 16 + t16;
                    s16x8 bv = *(const s16x8*)(Vl + e * 512 + (((tg >> 3) ^ (e & 7)) << 3));
                    oacc[eo] = mfma_bf16(pa, bv, oacc[eo]);
                }
            }
        }
        #pragma unroll
        for (int eo = 0; eo < 4; ++eo)
            #pragma unroll
            for (int r_ = 0; r_ < 4; ++r_) {
                int row = q0 + g * 4 + r_;
                int e = eo * 16 + t16;
                size_t idx = ((size_t)b * SS + row) * DD + h * HDH + e;
                float val = oacc[eo][r_];
                unsigned short hi = f2bf(val);
                oh[idx] = hi;
                ol[idx] = f2bf(val - bf2f(hi));
            }
    }
}

extern "C" void kernel_launch(void* const* d_in, const int* in_sizes, int n_in,
                              void* d_out, int out_size, void* d_ws, size_t ws_size,
                              hipStream_t stream)
{
    const int*   tokens = (const int*)d_in[0];
    const int*   mask   = (const int*)d_in[1];
    const float* emb    = (const float*)d_in[2];
    const float* pe     = (const float*)d_in[3];
    const float* Wq     = (const float*)d_in[4];
    const float* Wk     = (const float*)d_in[5];
    const float* Wv     = (const float*)d_in[6];
    const float* Wo     = (const float*)d_in[7];
    const float* l1g    = (const float*)d_in[8];
    const float* l1b    = (const float*)d_in[9];
    const float* W1     = (const float*)d_in[10];
    const float* b1     = (const float*)d_in[11];
    const float* W2     = (const float*)d_in[12];
    const float* b2     = (const float*)d_in[13];
    const float* l2g    = (const float*)d_in[14];
    const float* l2b    = (const float*)d_in[15];

    char* p = (char*)d_ws;
    auto alloc = [&](size_t bytes) { char* r = p; p += (bytes + 255) & ~(size_t)255; return r; };
    unsigned short* wq_t = (unsigned short*)alloc((size_t)LL*DD*DD*2);
    unsigned short* wk_t = (unsigned short*)alloc((size_t)LL*DD*DD*2);
    unsigned short* wv_t = (unsigned short*)alloc((size_t)LL*DD*DD*2);
    unsigned short* wo_t = (unsigned short*)alloc((size_t)LL*DD*DD*2);
    unsigned short* w1_t = (unsigned short*)alloc((size_t)LL*DD*DFF*2);
    unsigned short* w2_t = (unsigned short*)alloc((size_t)LL*DD*DFF*2);
    float*          x    = (float*)alloc((size_t)MM*DD*4);
    unsigned short* xh   = (unsigned short*)alloc((size_t)MM*DD*2);
    unsigned short* xl   = (unsigned short*)alloc((size_t)MM*DD*2);
    unsigned short* r4   = (unsigned short*)alloc((size_t)MM*DD*2); // q   | y lo-half
    unsigned short* r5   = (unsigned short*)alloc((size_t)MM*DD*2); // k   | y hi-half
    unsigned short* r6   = (unsigned short*)alloc((size_t)MM*DD*2); // v   | h[0]
    unsigned short* r7   = (unsigned short*)alloc((size_t)MM*DD*2); // o_h | h[1]
    unsigned short* r8   = (unsigned short*)alloc((size_t)MM*DD*2); // o_l | h[2]
    unsigned short* r9   = (unsigned short*)alloc((size_t)MM*DD*2); //     | h[3]
    float*          ybuf = (float*)r4;          // 32MB: aliases q,k (dead then)
    unsigned short* hbuf = r6;                  // 64MB: aliases v,o_h,o_l,r9

    k_conv_qkv<<<6144, 256, 0, stream>>>(Wq, wq_t);
    k_conv_qkv<<<6144, 256, 0, stream>>>(Wk, wk_t);
    k_conv_qkv<<<6144, 256, 0, stream>>>(Wv, wv_t);
    k_conv_t<<<6144, 256, 0, stream>>>(Wo, wo_t, 9, 9);
    k_conv_t<<<24576, 256, 0, stream>>>(W1, w1_t, 9, 11);
    k_conv_t<<<24576, 256, 0, stream>>>(W2, w2_t, 11, 9);
    k_embed<<<8192, 256, 0, stream>>>(tokens, emb, pe, x, xh, xl);

    hipFuncSetAttribute((const void*)k_attn,
                        hipFuncAttributeMaxDynamicSharedMemorySize, 147456);

    for (int l = 0; l < LL; ++l) {
        const unsigned short* wql = wq_t + (size_t)l*DD*DD;
        const unsigned short* wkl = wk_t + (size_t)l*DD*DD;
        const unsigned short* wvl = wv_t + (size_t)l*DD*DD;
        const unsigned short* wol = wo_t + (size_t)l*DD*DD;
        const unsigned short* w1l = w1_t + (size_t)l*DD*DFF;
        const unsigned short* w2l = w2_t + (size_t)l*DD*DFF;

        k_gemm<0, true><<<512, 256, 0, stream>>>(xh, xl, wql, r4, nullptr, nullptr, 512, 512, 2);
        k_gemm<0, true><<<512, 256, 0, stream>>>(xh, xl, wkl, r5, nullptr, nullptr, 512, 512, 2);
        k_gemm<0, true><<<512, 256, 0, stream>>>(xh, xl, wvl, r6, nullptr, nullptr, 512, 512, 2);
        k_attn<<<256, 512, 147456, stream>>>(r4, r5, r6, mask, r7, r8);
        k_gemm<1, true><<<512, 256, 0, stream>>>(r7, r8, wol, nullptr, ybuf, nullptr, 512, 512, 2);
        k_ln<<<16384, 128, 0, stream>>>(x, ybuf, l1g + l*DD, l1b + l*DD, x, xh, xl);
        k_gemm<2, true><<<2048, 256, 0, stream>>>(xh, xl, w1l, hbuf, nullptr, b1 + (size_t)l*DFF, 2048, 512, 4);
        k_gemm<3, false><<<512, 256, 0, stream>>>(hbuf, nullptr, w2l, nullptr, ybuf, b2 + (size_t)l*DD, 512, 2048, 2);
        float* xout = (l == LL - 1) ? (float*)d_out : x;
        k_ln<<<16384, 128, 0, stream>>>(x, ybuf, l2g + l*DD, l2b + l*DD, xout, xh, xl);
    }
}

// Round 2
// 1504.072 us; speedup vs baseline: 1.3335x; 1.3335x over previous
//
// EncoderModel forward, MI355X/gfx950. Round 2: drop split-A (bf16 activations),
// fused QKV GEMM (N=1536), flash-style attention with 16 waves + 160KB LDS.
#include <hip/hip_runtime.h>

#define BB 32
#define SS 512
#define DD 512
#define HH 8
#define HDH 64
#define LL 6
#define DFF 2048
#define MM (BB*SS)

typedef __attribute__((ext_vector_type(4))) float f32x4;
typedef __attribute__((ext_vector_type(8))) short s16x8;
typedef __attribute__((ext_vector_type(4))) short s16x4;

__device__ __forceinline__ unsigned short f2bf(float f) {
    union { float f; unsigned u; } v; v.f = f;
    unsigned r = v.u + 0x7fffu + ((v.u >> 16) & 1u);
    return (unsigned short)(r >> 16);
}
__device__ __forceinline__ float bf2f(unsigned short b) {
    union { unsigned u; float f; } v; v.u = ((unsigned)b) << 16;
    return v.f;
}

__device__ __forceinline__ f32x4 mfma_bf16(s16x8 a, s16x8 b, f32x4 c) {
    asm("v_mfma_f32_16x16x32_bf16 %0, %1, %2, %0" : "+v"(c) : "v"(a), "v"(b));
    return c;
}

__device__ __forceinline__ void gload_lds16(const void* g, void* l) {
    __builtin_amdgcn_global_load_lds(
        (__attribute__((address_space(1))) void*)g,
        (__attribute__((address_space(3))) void*)l, 16, 0, 0);
}

// ---- Wq/Wk/Wv [L][H][D][HD] -> fused bf16 [L][1536][512] (q|k|v per layer) --
__global__ __launch_bounds__(256) void k_conv_qkv3(const float* __restrict__ Wq,
                                                   const float* __restrict__ Wk,
                                                   const float* __restrict__ Wv,
                                                   unsigned short* __restrict__ dst) {
    int i = blockIdx.x * 256 + threadIdx.x;          // over L*1536*512
    if (i >= LL*3*DD*DD) return;
    int l = i / (3*DD*DD);
    int rem = i - l*(3*DD*DD);
    int n = rem >> 9;
    int kk = rem & 511;
    int which = n >> 9;
    int h = (n >> 6) & 7, e = n & 63;
    const float* W = which == 0 ? Wq : (which == 1 ? Wk : Wv);
    dst[i] = f2bf(W[(((size_t)l*HH + h)*DD + kk)*HDH + e]);
}

// ---- generic: src [L][K][N] f32 -> dst [L][N][K] bf16 (K,N powers of 2) ----
__global__ __launch_bounds__(256) void k_conv_t(const float* __restrict__ src,
                                                unsigned short* __restrict__ dst,
                                                int logK, int logN) {
    int i = blockIdx.x * 256 + threadIdx.x;
    if (i >= (LL << (logK + logN))) return;
    int l = i >> (logK + logN);
    int n = (i >> logK) & ((1 << logN) - 1);
    int kk = i & ((1 << logK) - 1);
    dst[i] = f2bf(src[((size_t)l << (logK + logN)) + ((size_t)kk << logN) + n]);
}

// ---- embedding + positional encoding; writes f32 x and bf16 copy ----------
__global__ __launch_bounds__(256) void k_embed(const int* __restrict__ tokens,
                                               const float* __restrict__ emb,
                                               const float* __restrict__ pe,
                                               float* __restrict__ x,
                                               unsigned short* __restrict__ xh) {
    int i = blockIdx.x * 256 + threadIdx.x;          // MM*128 float4's
    int row = i >> 7;
    int d4 = (i & 127) * 4;
    int srow = row & (SS - 1);
    int tok = tokens[row];
    f32x4 ev = *(const f32x4*)(emb + (size_t)tok*DD + d4);
    f32x4 pv = *(const f32x4*)(pe + (size_t)srow*DD + d4);
    f32x4 vv; s16x4 hv;
    #pragma unroll
    for (int j = 0; j < 4; ++j) {
        vv[j] = ev[j] + pv[j];
        hv[j] = (short)f2bf(vv[j]);
    }
    *(f32x4*)(x + (size_t)row*DD + d4) = vv;
    *(s16x4*)(xh + (size_t)row*DD + d4) = hv;
}

// ---- fused residual + layernorm; writes f32 x_out and bf16 copy -----------
__global__ __launch_bounds__(128) void k_ln(const float* __restrict__ x,
                                            const float* __restrict__ y,
                                            const float* __restrict__ gg,
                                            const float* __restrict__ bb,
                                            float* __restrict__ xo,
                                            unsigned short* __restrict__ xh) {
    const int row = blockIdx.x;
    const int tid = threadIdx.x;
    __shared__ float red[4];
    f32x4 xv = *(const f32x4*)(x + (size_t)row*DD + tid*4);
    f32x4 yv = *(const f32x4*)(y + (size_t)row*DD + tid*4);
    f32x4 vv;
    #pragma unroll
    for (int j = 0; j < 4; ++j) vv[j] = xv[j] + yv[j];
    float sum = vv[0] + vv[1] + vv[2] + vv[3];
    #pragma unroll
    for (int off = 1; off < 64; off <<= 1) sum += __shfl_xor(sum, off);
    if ((tid & 63) == 0) red[tid >> 6] = sum;
    __syncthreads();
    float mu = (red[0] + red[1]) * (1.0f / 512.0f);
    float s2 = 0.0f;
    #pragma unroll
    for (int j = 0; j < 4; ++j) { float d = vv[j] - mu; s2 += d * d; }
    #pragma unroll
    for (int off = 1; off < 64; off <<= 1) s2 += __shfl_xor(s2, off);
    if ((tid & 63) == 0) red[2 + (tid >> 6)] = s2;
    __syncthreads();
    float var = (red[2] + red[3]) * (1.0f / 512.0f);
    float rs = rsqrtf(var + 1e-5f);
    f32x4 gv = *(const f32x4*)(gg + tid*4);
    f32x4 bv = *(const f32x4*)(bb + tid*4);
    f32x4 ov; s16x4 hv;
    #pragma unroll
    for (int j = 0; j < 4; ++j) {
        float o = (vv[j] - mu) * rs * gv[j] + bv[j];
        ov[j] = o;
        hv[j] = (short)f2bf(o);
    }
    *(f32x4*)(xo + (size_t)row*DD + tid*4) = ov;
    *(s16x4*)(xh + (size_t)row*DD + tid*4) = hv;
}

// ---- GEMM: C[M,N] = A[M,K] @ Bt[N,K]^T, bf16 MFMA 16x16x32 ----------------
// EPI: 0 = bf16 out, 1 = f32 out, 2 = bf16 gelu(out+bias), 3 = f32 out+bias
template<int EPI>
__global__ __launch_bounds__(256, 2) void k_gemm(
    const unsigned short* __restrict__ A, const unsigned short* __restrict__ Bt,
    unsigned short* __restrict__ ob, float* __restrict__ of,
    const float* __restrict__ bias, int N, int K, int nt)
{
    __shared__ short lds[2][2][4096];   // [buf][A,B][128 rows x 32 bf16]
    const int tid = threadIdx.x;
    const int lane = tid & 63;
    const int wid = tid >> 6;
    const int g = lane >> 4;
    const int t16 = lane & 15;

    // XCD-aware bijective swizzle (grid always divisible by 8 here)
    int nwg = gridDim.x;
    int bid = blockIdx.x;
    int cpx = nwg >> 3;
    int swz = (bid & 7) * cpx + (bid >> 3);
    int bm = swz / nt;
    int bn = swz - bm * nt;

    const unsigned short* Ag = A  + (size_t)bm * 128 * K;
    const unsigned short* Bg = Bt + (size_t)bn * 128 * K;

    auto stage = [&](int buf, int k0) {
        #pragma unroll
        for (int i = 0; i < 2; ++i) {
            int slot = i * 256 + tid;
            int r = slot >> 2;
            int j = slot & 3;
            int js = j ^ ((r >> 1) & 3);       // source-side swizzle (involution)
            size_t go = (size_t)r * K + k0 + js * 8;
            int lo = i * 2048 + wid * 512;     // wave-uniform LDS base (shorts)
            gload_lds16(Ag + go, &lds[buf][0][lo]);
            gload_lds16(Bg + go, &lds[buf][1][lo]);
        }
    };

    f32x4 acc[4][4];
    #pragma unroll
    for (int a_ = 0; a_ < 4; ++a_)
        #pragma unroll
        for (int b_ = 0; b_ < 4; ++b_) acc[a_][b_] = (f32x4){0.f, 0.f, 0.f, 0.f};

    const int wm = wid >> 1, wn = wid & 1;
    stage(0, 0);
    __syncthreads();
    int nk = K >> 5;
    int buf = 0;
    for (int kt = 0; kt < nk; ++kt) {
        if (kt + 1 < nk) stage(buf ^ 1, (kt + 1) << 5);
        s16x8 af[4], bf_[4];
        #pragma unroll
        for (int mt = 0; mt < 4; ++mt) {
            int r = wm * 64 + mt * 16 + t16;
            af[mt] = *(const s16x8*)&lds[buf][0][r * 32 + ((g ^ ((r >> 1) & 3)) << 3)];
        }
        #pragma unroll
        for (int nt_ = 0; nt_ < 4; ++nt_) {
            int r = wn * 64 + nt_ * 16 + t16;
            bf_[nt_] = *(const s16x8*)&lds[buf][1][r * 32 + ((g ^ ((r >> 1) & 3)) << 3)];
        }
        #pragma unroll
        for (int mt = 0; mt < 4; ++mt)
            #pragma unroll
            for (int nt_ = 0; nt_ < 4; ++nt_)
                acc[mt][nt_] = mfma_bf16(af[mt], bf_[nt_], acc[mt][nt_]);
        __syncthreads();
        buf ^= 1;
    }

    #pragma unroll
    for (int mt = 0; mt < 4; ++mt)
        #pragma unroll
        for (int nt_ = 0; nt_ < 4; ++nt_) {
            int row0 = bm * 128 + wm * 64 + mt * 16 + g * 4;
            int col  = bn * 128 + wn * 64 + nt_ * 16 + t16;
            f32x4 v = acc[mt][nt_];
            float bv = (EPI == 2 || EPI == 3) ? bias[col] : 0.0f;
            #pragma unroll
            for (int r_ = 0; r_ < 4; ++r_) {
                size_t idx = (size_t)(row0 + r_) * N + col;
                if (EPI == 0) {
                    ob[idx] = f2bf(v[r_]);
                } else if (EPI == 1) {
                    of[idx] = v[r_];
                } else if (EPI == 2) {
                    float tv = v[r_] + bv;
                    float ge = 0.5f * tv * (1.0f + erff(tv * 0.70710678118f));
                    ob[idx] = f2bf(ge);
                } else {
                    of[idx] = v[r_] + bv;
                }
            }
        }
}

// ---- attention: 1 block/(b,h), 16 waves, flash-style over 128-key chunks --
// LDS 160KB: K [512][64] swizzled (64KB) + V^T [64][512] swizzled (64KB)
//            + per-wave P [16][64] (32KB)
__global__ __launch_bounds__(1024, 4) void k_attn(
    const unsigned short* __restrict__ qkv, const int* __restrict__ mask,
    unsigned short* __restrict__ o)
{
    extern __shared__ short smem[];
    short* Kl = smem;                        // [512][64], blk j ^= (t&7)
    short* Vl = smem + 32768;                // [64][512], blk ^= (e&7)^((e>>3)&7)
    const int tid = threadIdx.x;
    const int lane = tid & 63, wid = tid >> 6;
    short* Pl = smem + 65536 + wid * 1024;   // per-wave [16][64]
    const int b = blockIdx.x >> 3, h = blockIdx.x & 7;
    const unsigned short* base = qkv + (size_t)b * SS * 1536;
    const int qc = h * 64, kc = 512 + h * 64, vc = 1024 + h * 64;

    // stage K (vectorized, swizzled)
    for (int c = tid; c < 4096; c += 1024) {
        int t = c >> 3, j = c & 7;
        s16x8 kv = *(const s16x8*)(base + (size_t)t * 1536 + kc + j * 8);
        *(s16x8*)(Kl + t * 64 + ((j ^ (t & 7)) << 3)) = kv;
    }
    // stage V^T via register 8x8 transpose (half-tile of 4 rows per thread)
    {
        int unit = tid >> 1, half = tid & 1;
        int t0 = (unit >> 3) << 3, e0 = (unit & 7) << 3;
        s16x8 r0 = *(const s16x8*)(base + (size_t)(t0 + half*4 + 0) * 1536 + vc + e0);
        s16x8 r1 = *(const s16x8*)(base + (size_t)(t0 + half*4 + 1) * 1536 + vc + e0);
        s16x8 r2 = *(const s16x8*)(base + (size_t)(t0 + half*4 + 2) * 1536 + vc + e0);
        s16x8 r3 = *(const s16x8*)(base + (size_t)(t0 + half*4 + 3) * 1536 + vc + e0);
        #pragma unroll
        for (int j = 0; j < 8; ++j) {
            int e = e0 + j;
            int slot = (t0 >> 3) ^ (e & 7) ^ ((e >> 3) & 7);
            s16x4 w = (s16x4){r0[j], r1[j], r2[j], r3[j]};
            *(s16x4*)(Vl + e * 512 + (slot << 3) + (half << 2)) = w;
        }
    }
    const int g = lane >> 4, t16 = lane & 15;
    unsigned mbits = 0;
    for (int n2 = 0; n2 < 32; ++n2)
        if (mask[b * SS + n2 * 16 + t16] != 0) mbits |= (1u << n2);
    __syncthreads();

    for (int qi = 0; qi < 2; ++qi) {
        const int q0 = (wid * 2 + qi) * 16;
        s16x8 aq[2];
        #pragma unroll
        for (int ks = 0; ks < 2; ++ks)
            aq[ks] = *(const s16x8*)(base + (size_t)(q0 + t16) * 1536 + qc + ks * 32 + g * 8);

        f32x4 oacc[4];
        #pragma unroll
        for (int eo = 0; eo < 4; ++eo) oacc[eo] = (f32x4){0.f, 0.f, 0.f, 0.f};
        float mx[4] = {-3.0e38f, -3.0e38f, -3.0e38f, -3.0e38f};
        float ls[4] = {0.f, 0.f, 0.f, 0.f};

        for (int tc = 0; tc < 4; ++tc) {          // 128-key chunks
            f32x4 s[8];
            #pragma unroll
            for (int n2 = 0; n2 < 8; ++n2) s[n2] = (f32x4){0.f, 0.f, 0.f, 0.f};
            #pragma unroll
            for (int n2 = 0; n2 < 8; ++n2) {
                int t = tc * 128 + n2 * 16 + t16;
                #pragma unroll
                for (int ks = 0; ks < 2; ++ks) {
                    int blk = ks * 4 + g;
                    s16x8 bk = *(const s16x8*)(Kl + t * 64 + ((blk ^ (t & 7)) << 3));
                    s[n2] = mfma_bf16(aq[ks], bk, s[n2]);
                }
            }
            #pragma unroll
            for (int n2 = 0; n2 < 8; ++n2) {
                bool val = (mbits >> (tc * 8 + n2)) & 1u;
                #pragma unroll
                for (int r_ = 0; r_ < 4; ++r_)
                    s[n2][r_] = val ? s[n2][r_] * 0.125f : -3.0e38f;
            }
            // chunk max + online rescale
            float sc[4];
            #pragma unroll
            for (int r_ = 0; r_ < 4; ++r_) {
                float m = s[0][r_];
                #pragma unroll
                for (int n2 = 1; n2 < 8; ++n2) m = fmaxf(m, s[n2][r_]);
                #pragma unroll
                for (int off = 1; off < 16; off <<= 1) m = fmaxf(m, __shfl_xor(m, off));
                float mn = fmaxf(mx[r_], m);
                sc[r_] = __expf(mx[r_] - mn);
                mx[r_] = mn;
                ls[r_] *= sc[r_];
            }
            #pragma unroll
            for (int eo = 0; eo < 4; ++eo)
                #pragma unroll
                for (int r_ = 0; r_ < 4; ++r_) oacc[eo][r_] *= sc[r_];
            // exp + row sums
            #pragma unroll
            for (int n2 = 0; n2 < 8; ++n2)
                #pragma unroll
                for (int r_ = 0; r_ < 4; ++r_)
                    s[n2][r_] = __expf(s[n2][r_] - mx[r_]);
            #pragma unroll
            for (int r_ = 0; r_ < 4; ++r_) {
                float t = 0.f;
                #pragma unroll
                for (int n2 = 0; n2 < 8; ++n2) t += s[n2][r_];
                #pragma unroll
                for (int off = 1; off < 16; off <<= 1) t += __shfl_xor(t, off);
                ls[r_] += t;
            }
            // P staging + PV over two 64-key sub-chunks
            #pragma unroll
            for (int c4 = 0; c4 < 2; ++c4) {
                #pragma unroll
                for (int k4 = 0; k4 < 4; ++k4) {
                    int n2 = c4 * 4 + k4;
                    #pragma unroll
                    for (int r_ = 0; r_ < 4; ++r_) {
                        int qq = g * 4 + r_;
                        int kk = k4 * 16 + t16;
                        Pl[qq * 64 + (((kk >> 3) ^ (qq & 7)) << 3) + (kk & 7)] =
                            (short)f2bf(s[n2][r_]);
                    }
                }
                #pragma unroll
                for (int ks2 = 0; ks2 < 2; ++ks2) {
                    int kk = ks2 * 32 + g * 8;
                    s16x8 pa = *(const s16x8*)(Pl + t16 * 64 + (((kk >> 3) ^ (t16 & 7)) << 3));
                    int tg = tc * 128 + c4 * 64 + kk;
                    #pragma unroll
                    for (int eo = 0; eo < 4; ++eo) {
                        int e = eo * 16 + t16;
                        int slot = (tg >> 3) ^ (e & 7) ^ ((e >> 3) & 7);
                        s16x8 bv = *(const s16x8*)(Vl + e * 512 + (slot << 3));
                        oacc[eo] = mfma_bf16(pa, bv, oacc[eo]);
                    }
                }
            }
        }
        // normalize + write bf16 o
        #pragma unroll
        for (int eo = 0; eo < 4; ++eo)
            #pragma unroll
            for (int r_ = 0; r_ < 4; ++r_) {
                int row = q0 + g * 4 + r_;
                int e = eo * 16 + t16;
                o[((size_t)b * SS + row) * DD + h * HDH + e] =
                    f2bf(oacc[eo][r_] / ls[r_]);
            }
    }
}

extern "C" void kernel_launch(void* const* d_in, const int* in_sizes, int n_in,
                              void* d_out, int out_size, void* d_ws, size_t ws_size,
                              hipStream_t stream)
{
    const int*   tokens = (const int*)d_in[0];
    const int*   mask   = (const int*)d_in[1];
    const float* emb    = (const float*)d_in[2];
    const float* pe     = (const float*)d_in[3];
    const float* Wq     = (const float*)d_in[4];
    const float* Wk     = (const float*)d_in[5];
    const float* Wv     = (const float*)d_in[6];
    const float* Wo     = (const float*)d_in[7];
    const float* l1g    = (const float*)d_in[8];
    const float* l1b    = (const float*)d_in[9];
    const float* W1     = (const float*)d_in[10];
    const float* b1     = (const float*)d_in[11];
    const float* W2     = (const float*)d_in[12];
    const float* b2     = (const float*)d_in[13];
    const float* l2g    = (const float*)d_in[14];
    const float* l2b    = (const float*)d_in[15];

    char* p = (char*)d_ws;
    auto alloc = [&](size_t bytes) { char* r = p; p += (bytes + 255) & ~(size_t)255; return r; };
    unsigned short* wqkv_t = (unsigned short*)alloc((size_t)LL*3*DD*DD*2);
    unsigned short* wo_t   = (unsigned short*)alloc((size_t)LL*DD*DD*2);
    unsigned short* w1_t   = (unsigned short*)alloc((size_t)LL*DD*DFF*2);
    unsigned short* w2_t   = (unsigned short*)alloc((size_t)LL*DD*DFF*2);
    float*          x      = (float*)alloc((size_t)MM*DD*4);
    unsigned short* xh     = (unsigned short*)alloc((size_t)MM*DD*2);
    unsigned short* qkvb   = (unsigned short*)alloc((size_t)MM*1536*2);
    unsigned short* obuf   = (unsigned short*)alloc((size_t)MM*DD*2);
    float*          ybuf   = (float*)alloc((size_t)MM*DD*4);
    unsigned short* hbuf   = qkvb;   // [MM][2048] aliases qkvb+obuf (67.1MB, dead then)

    k_conv_qkv3<<<18432, 256, 0, stream>>>(Wq, Wk, Wv, wqkv_t);
    k_conv_t<<<6144, 256, 0, stream>>>(Wo, wo_t, 9, 9);
    k_conv_t<<<24576, 256, 0, stream>>>(W1, w1_t, 9, 11);
    k_conv_t<<<24576, 256, 0, stream>>>(W2, w2_t, 11, 9);
    k_embed<<<8192, 256, 0, stream>>>(tokens, emb, pe, x, xh);

    hipFuncSetAttribute((const void*)k_attn,
                        hipFuncAttributeMaxDynamicSharedMemorySize, 163840);

    for (int l = 0; l < LL; ++l) {
        const unsigned short* wqkvl = wqkv_t + (size_t)l*3*DD*DD;
        const unsigned short* wol   = wo_t   + (size_t)l*DD*DD;
        const unsigned short* w1l   = w1_t   + (size_t)l*DD*DFF;
        const unsigned short* w2l   = w2_t   + (size_t)l*DD*DFF;

        k_gemm<0><<<1536, 256, 0, stream>>>(xh, wqkvl, qkvb, nullptr, nullptr, 1536, 512, 12);
        k_attn<<<256, 1024, 163840, stream>>>(qkvb, mask, obuf);
        k_gemm<1><<<512, 256, 0, stream>>>(obuf, wol, nullptr, ybuf, nullptr, 512, 512, 4);
        k_ln<<<16384, 128, 0, stream>>>(x, ybuf, l1g + l*DD, l1b + l*DD, x, xh);
        k_gemm<2><<<2048, 256, 0, stream>>>(xh, w1l, hbuf, nullptr, b1 + (size_t)l*DFF, 2048, 512, 16);
        k_gemm<3><<<512, 256, 0, stream>>>(hbuf, w2l, nullptr, ybuf, b2 + (size_t)l*DD, 512, 2048, 4);
        float* xout = (l == LL - 1) ? (float*)d_out : x;
        k_ln<<<16384, 128, 0, stream>>>(x, ybuf, l2g + l*DD, l2b + l*DD, xout, xh);
    }
}